// Round 1
// baseline (128.834 us; speedup 1.0000x reference)
//
#include <hip/hip_runtime.h>

// AttentionalPoolingMechanism: fused single-pass attention pooling.
// A[64,512] f32, B[64,8192,256] f32, W[256,512] f32, b[256] f32 -> out[64,1,256] f32.
//
// AP = tanh(A@W^T + b); s_t = <AP_b, B[b,t,:]>; w_t = exp(-s_t)/sum; out = sum_t w_t B[b,t,:]
// No max-subtraction needed (reference does bare exp(-R); |s| <~ 40 fits f32).

#define BATCH 64
#define T_LEN 8192
#define FEAT 512
#define HID 256
#define SPLIT 32                       // blocks per batch in pool pass
#define ROWS_PER_BLOCK (T_LEN / SPLIT) // 256
#define ROWS_PER_WAVE (ROWS_PER_BLOCK / 4) // 64

// ---------------- Kernel 1: AP = tanh(A @ W^T + bias) ----------------
// grid = BATCH blocks, 256 threads. Thread tid computes AP[b][tid].
// W tiles [256 x 32] staged coalesced into LDS with +1 pad (stride 33).
__global__ __launch_bounds__(256) void ap_kernel(const float* __restrict__ A,
                                                 const float* __restrict__ W,
                                                 const float* __restrict__ bias,
                                                 float* __restrict__ AP) {
    const int b = blockIdx.x;
    const int tid = threadIdx.x;

    __shared__ float sA[FEAT];
    __shared__ float sW[HID * 33]; // 256 rows x 32 k, padded stride 33 -> 2-way max (free)

    // stage A row (512 floats, 256 threads -> 2 each, coalesced)
    sA[tid] = A[b * FEAT + tid];
    sA[tid + 256] = A[b * FEAT + tid + 256];

    float acc = 0.0f;
    for (int k0 = 0; k0 < FEAT; k0 += 32) {
        __syncthreads(); // protects previous tile consumption (and sA stage on iter 0)
        // stage W[0:256][k0:k0+32] = 2048 float4, 8 per thread, coalesced in f-order
        #pragma unroll
        for (int t = 0; t < 8; ++t) {
            int f = t * 256 + tid;  // float4 index within tile
            int h = f >> 3;         // row
            int kq = f & 7;         // which float4 within the 32-wide row chunk
            float4 v = *(const float4*)(W + (size_t)h * FEAT + k0 + kq * 4);
            float* dst = &sW[h * 33 + kq * 4];
            dst[0] = v.x; dst[1] = v.y; dst[2] = v.z; dst[3] = v.w;
        }
        __syncthreads();
        #pragma unroll
        for (int k = 0; k < 32; ++k)
            acc += sA[k0 + k] * sW[tid * 33 + k];
    }
    acc += bias[tid];
    AP[b * HID + tid] = tanhf(acc);
}

// ---------------- Kernel 2: fused score+exp+weighted-accumulate ----------------
// grid = (SPLIT, BATCH), 256 threads = 4 waves. Wave owns 64 consecutive rows.
// Per row: coalesced float4 load (64 lanes x 16B = full 1KB row), dot vs AP frag,
// wave allreduce, w = exp(-s), accumulate w*v into 4 per-lane registers.
__global__ __launch_bounds__(256) void pool_kernel(const float* __restrict__ B,
                                                   const float* __restrict__ AP,
                                                   float* __restrict__ numP,
                                                   float* __restrict__ denP) {
    const int split = blockIdx.x;
    const int b = blockIdx.y;
    const int tid = threadIdx.x;
    const int wv = tid >> 6;
    const int lane = tid & 63;

    // per-lane AP fragment: h = lane*4 .. lane*4+3 (64 KB total, L2-resident)
    const float4 ap = *(const float4*)(AP + b * HID + lane * 4);
    const float4* __restrict__ B4 = (const float4*)(B) + (size_t)b * T_LEN * (HID / 4);

    const int row0 = split * ROWS_PER_BLOCK + wv * ROWS_PER_WAVE;

    float4 acc = {0.f, 0.f, 0.f, 0.f};
    float den = 0.0f;

    #pragma unroll 4
    for (int r = 0; r < ROWS_PER_WAVE; ++r) {
        float4 v = B4[(size_t)(row0 + r) * (HID / 4) + lane];
        float p = v.x * ap.x + v.y * ap.y + v.z * ap.z + v.w * ap.w;
        #pragma unroll
        for (int m = 32; m >= 1; m >>= 1) p += __shfl_xor(p, m, 64);
        float w = __expf(-p);
        acc.x += w * v.x;
        acc.y += w * v.y;
        acc.z += w * v.z;
        acc.w += w * v.w;
        den += w; // identical across lanes after allreduce
    }

    // combine 4 waves via LDS, write per-block partials
    __shared__ float s_num[4][HID];
    __shared__ float s_den[4];
    *(float4*)&s_num[wv][lane * 4] = acc;
    if (lane == 0) s_den[wv] = den;
    __syncthreads();

    const int blk = b * SPLIT + split;
    float n = s_num[0][tid] + s_num[1][tid] + s_num[2][tid] + s_num[3][tid];
    numP[(size_t)blk * HID + tid] = n;
    if (tid == 0) denP[blk] = s_den[0] + s_den[1] + s_den[2] + s_den[3];
}

// ---------------- Kernel 3: reduce partials, normalize ----------------
__global__ __launch_bounds__(256) void reduce_kernel(const float* __restrict__ numP,
                                                     const float* __restrict__ denP,
                                                     float* __restrict__ out) {
    const int b = blockIdx.x;
    const int h = threadIdx.x;
    float num = 0.0f, den = 0.0f;
    #pragma unroll
    for (int s = 0; s < SPLIT; ++s) {
        num += numP[(size_t)(b * SPLIT + s) * HID + h];
        den += denP[b * SPLIT + s]; // same addr across threads -> broadcast
    }
    out[b * HID + h] = num / den;
}

extern "C" void kernel_launch(void* const* d_in, const int* in_sizes, int n_in,
                              void* d_out, int out_size, void* d_ws, size_t ws_size,
                              hipStream_t stream) {
    const float* A = (const float*)d_in[0];    // [64,512]
    const float* B = (const float*)d_in[1];    // [64,8192,256]
    const float* W = (const float*)d_in[2];    // [256,512]
    const float* bias = (const float*)d_in[3]; // [256]
    float* out = (float*)d_out;                // [64,1,256]

    // workspace layout (floats): AP[64*256] | numP[2048*256] | denP[2048]  (~2.2 MB)
    float* AP = (float*)d_ws;
    float* numP = AP + BATCH * HID;
    float* denP = numP + BATCH * SPLIT * HID;

    ap_kernel<<<BATCH, 256, 0, stream>>>(A, W, bias, AP);
    pool_kernel<<<dim3(SPLIT, BATCH), 256, 0, stream>>>(B, AP, numP, denP);
    reduce_kernel<<<BATCH, 256, 0, stream>>>(numP, denP, out);
}